// Round 1
// baseline (349.922 us; speedup 1.0000x reference)
//
#include <hip/hip_runtime.h>
#include <hip/hip_bf16.h>

#define D_DIM 128
#define TILE 128

typedef __attribute__((ext_vector_type(8))) short short8;   // 8 bf16 in 4 VGPRs (MFMA A/B frag)
typedef __attribute__((ext_vector_type(4))) float floatx4;  // MFMA C/D frag

// ---------------------------------------------------------------------------
// prep: round fp32 rows to bf16 (stored to ws) and compute row sum-of-squares
// of the ROUNDED values (so d2 = ||a_hat - b_hat||^2 >= 0 exactly).
// 64 lanes per row, 2 elements per lane; 4 rows per 256-thread block.
// ---------------------------------------------------------------------------
__global__ void prep_kernel(const float* __restrict__ za, const float* __restrict__ zb,
                            __hip_bfloat16* __restrict__ abf, __hip_bfloat16* __restrict__ bbf,
                            float* __restrict__ a2, float* __restrict__ b2, int N) {
    int r = blockIdx.x * 4 + (threadIdx.x >> 6);
    int lane = threadIdx.x & 63;
    const float* src; __hip_bfloat16* dst; float* nrm; int row;
    if (r < N) { src = za; dst = abf; nrm = a2; row = r; }
    else       { src = zb; dst = bbf; nrm = b2; row = r - N; }
    const float2 v = ((const float2*)(src + (size_t)row * D_DIM))[lane];
    __hip_bfloat16 h0 = __float2bfloat16(v.x);
    __hip_bfloat16 h1 = __float2bfloat16(v.y);
    float f0 = __bfloat162float(h0), f1 = __bfloat162float(h1);
    float ss = f0 * f0 + f1 * f1;
    ushort2 st;
    st.x = *(const unsigned short*)&h0;
    st.y = *(const unsigned short*)&h1;
    ((ushort2*)(dst + (size_t)row * D_DIM))[lane] = st;
    #pragma unroll
    for (int off = 32; off; off >>= 1) ss += __shfl_down(ss, off, 64);
    if (lane == 0) nrm[row] = ss;
}

// ---------------------------------------------------------------------------
// dist v2: NO LDS. Inputs (4 MB bf16 total) are L2/L3-resident -- fragments
// load straight from global (16 B/lane, 16x64B segments per wave inst).
// Removing LDS kills the stage->vmcnt(0)->barrier serialization and lifts
// the LDS occupancy cap (69.6 KB/block -> 0); __launch_bounds__(256,3)
// gives 3 blocks/CU (12 waves/CU) for latency hiding.
//
// OPERAND SWAP: acc = mfma(frag_from_bbf, frag_from_abf, acc) so
//   D row  = (lane>>4)*4 + reg  -> m (z_pos_neg index, contiguous in out row)
//   D col  = lane&15            -> n (z_anc index)
// => each lane's 4 acc regs are 4 consecutive m: epilogue stores float4
// (16 insts/thread instead of 64 scalar dwords), b2 loads as float4.
//
// Verified gfx950 layouts (learn_hip m89/m91):
//   A frag: lane holds A[r = lane&15][k = (lane>>4)*8 + t], t=0..7 contiguous
//   B frag: lane holds B[c = lane&15][k = (lane>>4)*8 + t]
//   C/D:    col = lane&15, row = (lane>>4)*4 + reg
// ---------------------------------------------------------------------------
__global__ __launch_bounds__(256, 3)
void dist_kernel(const __hip_bfloat16* __restrict__ abf, const __hip_bfloat16* __restrict__ bbf,
                 const float* __restrict__ a2, const float* __restrict__ b2,
                 float* __restrict__ out, int M) {
    const int rowBase = blockIdx.y * TILE;   // n: into z_anc
    const int colBase = blockIdx.x * TILE;   // m: into z_pos_neg
    const int tid  = threadIdx.x;
    const int wave = tid >> 6;
    const int lane = tid & 63;
    const int wn = (wave >> 1) * 64;         // wave n-offset in tile
    const int wm = (wave & 1) * 64;          // wave m-offset in tile
    const int lrow = lane & 15;
    const int lk8  = (lane >> 4) * 8;

    // element offsets (int: max 8192*128 = 2^20, no overflow) -> compiler
    // emits saddr-base + 32-bit voffset loads, k-step folds into imm offset
    int aOff[4], bOff[4];
    #pragma unroll
    for (int j = 0; j < 4; ++j) {
        aOff[j] = (rowBase + wn + j * 16 + lrow) * D_DIM;   // B operand (n)
        bOff[j] = (colBase + wm + j * 16 + lrow) * D_DIM;   // A operand (m)
    }

    floatx4 acc[4][4] = {};   // acc[jm][jn]
    #pragma unroll
    for (int ks = 0; ks < 4; ++ks) {
        const int k0 = ks * 32 + lk8;
        short8 afr[4], bfr[4];
        #pragma unroll
        for (int jm = 0; jm < 4; ++jm)
            afr[jm] = *(const short8*)(bbf + (bOff[jm] + k0));
        #pragma unroll
        for (int jn = 0; jn < 4; ++jn)
            bfr[jn] = *(const short8*)(abf + (aOff[jn] + k0));
        #pragma unroll
        for (int jm = 0; jm < 4; ++jm)
            #pragma unroll
            for (int jn = 0; jn < 4; ++jn)
                acc[jm][jn] = __builtin_amdgcn_mfma_f32_16x16x32_bf16(afr[jm], bfr[jn], acc[jm][jn], 0, 0, 0);
    }

    // Epilogue: out[n][m0..m0+3] = -sqrt(max(a2[n] + b2[m] - 2*ab, 0)), float4
    const int mq = (lane >> 4) * 4;
    float an[4];
    size_t rowOff[4];
    #pragma unroll
    for (int jn = 0; jn < 4; ++jn) {
        const int n = rowBase + wn + jn * 16 + lrow;
        an[jn] = a2[n];
        rowOff[jn] = (size_t)n * (size_t)M;
    }
    #pragma unroll
    for (int jm = 0; jm < 4; ++jm) {
        const int m0 = colBase + wm + jm * 16 + mq;
        const floatx4 bq = *(const floatx4*)(b2 + m0);
        #pragma unroll
        for (int jn = 0; jn < 4; ++jn) {
            floatx4 v;
            #pragma unroll
            for (int r = 0; r < 4; ++r) {
                float d2 = an[jn] + bq[r] - 2.0f * acc[jm][jn][r];
                d2 = fmaxf(d2, 0.0f);
                v[r] = -sqrtf(d2);
            }
            *(floatx4*)(out + rowOff[jn] + m0) = v;
        }
    }
}

extern "C" void kernel_launch(void* const* d_in, const int* in_sizes, int n_in,
                              void* d_out, int out_size, void* d_ws, size_t ws_size,
                              hipStream_t stream) {
    const float* za = (const float*)d_in[0];
    const float* zb = (const float*)d_in[1];
    const int N = in_sizes[0] / D_DIM;   // 8192
    const int M = in_sizes[1] / D_DIM;   // 8192
    float* out = (float*)d_out;

    // workspace layout: abf [N*128 bf16] | bbf [M*128 bf16] | a2 [N f32] | b2 [M f32]
    char* ws = (char*)d_ws;
    __hip_bfloat16* abf = (__hip_bfloat16*)ws;
    __hip_bfloat16* bbf = (__hip_bfloat16*)(ws + (size_t)N * D_DIM * sizeof(__hip_bfloat16));
    float* a2 = (float*)(ws + (size_t)(N + M) * D_DIM * sizeof(__hip_bfloat16));
    float* b2 = a2 + N;

    prep_kernel<<<(N + M) / 4, 256, 0, stream>>>(za, zb, abf, bbf, a2, b2, N);

    dim3 grid(M / TILE, N / TILE);
    dist_kernel<<<grid, 256, 0, stream>>>(abf, bbf, a2, b2, out, M);
}

// Round 3
// 330.675 us; speedup vs baseline: 1.0582x; 1.0582x over previous
//
#include <hip/hip_runtime.h>
#include <hip/hip_bf16.h>

#define D_DIM 128
#define TILE 128
#define LT_PAD 4   // +4 floats/row: rotates banks across rows, keeps b128 writes 2-way (free)

typedef __attribute__((ext_vector_type(8))) short short8;   // 8 bf16 in 4 VGPRs (MFMA A/B frag)
typedef __attribute__((ext_vector_type(4))) float floatx4;  // MFMA C/D frag

// ---------------------------------------------------------------------------
// prep: round fp32 rows to bf16 (stored to ws) and compute row sum-of-squares
// of the ROUNDED values (so d2 = ||a_hat - b_hat||^2 >= 0 exactly).
// ---------------------------------------------------------------------------
__global__ void prep_kernel(const float* __restrict__ za, const float* __restrict__ zb,
                            __hip_bfloat16* __restrict__ abf, __hip_bfloat16* __restrict__ bbf,
                            float* __restrict__ a2, float* __restrict__ b2, int N) {
    int r = blockIdx.x * 4 + (threadIdx.x >> 6);
    int lane = threadIdx.x & 63;
    const float* src; __hip_bfloat16* dst; float* nrm; int row;
    if (r < N) { src = za; dst = abf; nrm = a2; row = r; }
    else       { src = zb; dst = bbf; nrm = b2; row = r - N; }
    const float2 v = ((const float2*)(src + (size_t)row * D_DIM))[lane];
    __hip_bfloat16 h0 = __float2bfloat16(v.x);
    __hip_bfloat16 h1 = __float2bfloat16(v.y);
    float f0 = __bfloat162float(h0), f1 = __bfloat162float(h1);
    float ss = f0 * f0 + f1 * f1;
    ushort2 st;
    st.x = *(const unsigned short*)&h0;
    st.y = *(const unsigned short*)&h1;
    ((ushort2*)(dst + (size_t)row * D_DIM))[lane] = st;
    #pragma unroll
    for (int off = 32; off; off >>= 1) ss += __shfl_down(ss, off, 64);
    if (lane == 0) nrm[row] = ss;
}

// ---------------------------------------------------------------------------
// dist v3: direct-from-L2 input fragments (round-1, proven neutral-or-better)
// + LDS-TRANSPOSE EPILOGUE. A 16x16 MFMA fragment scatters its tile across
// lanes such that any direct store instruction covers >=16 rows with <=64B
// per row. Instead: compute -sqrt(max(a2+b2-2ab,0)) in regs, bounce the
// block's 128x128 result through a 64x128 f32 LDS buffer (2 chunks), and
// store cooperatively -- each store inst then covers 2 rows x 512B contiguous
// (8x the segment size, full L2 lines). LDS volume 268 MB @ >=40 TB/s ~ 7us.
// Stores are nontemporal (out is never re-read; keep bf16 inputs L2-resident).
// __builtin_amdgcn_sqrtf (v_sqrt_f32, ~1 ULP) replaces the IEEE sqrtf
// expansion -- tolerance is dominated by bf16 rounding (absmax 0.125).
//
// Verified gfx950 layouts (learn_hip m89/m91), operand-swapped:
//   acc = mfma(frag from bbf (m rows), frag from abf (n rows))
//   acc[jm][jn][r] <-> m_local = wm + jm*16 + (lane>>4)*4 + r
//                      n_local = wn + jn*16 + (lane&15)
// ---------------------------------------------------------------------------
__global__ __launch_bounds__(256, 3)
void dist_kernel(const __hip_bfloat16* __restrict__ abf, const __hip_bfloat16* __restrict__ bbf,
                 const float* __restrict__ a2, const float* __restrict__ b2,
                 float* __restrict__ out, int M) {
    __shared__ float lt[64][128 + LT_PAD];   // 33.8 KB -> LDS allows 4 blocks/CU; VGPR gives 3

    const int rowBase = blockIdx.y * TILE;   // n: into z_anc
    const int colBase = blockIdx.x * TILE;   // m: into z_pos_neg
    const int tid  = threadIdx.x;
    const int wave = tid >> 6;
    const int lane = tid & 63;
    const int wn = (wave >> 1) * 64;         // wave n-offset in tile
    const int wm = (wave & 1) * 64;          // wave m-offset in tile
    const int lrow = lane & 15;
    const int lk8  = (lane >> 4) * 8;
    const int mq   = (lane >> 4) * 4;

    // element offsets (max 8192*128 = 2^20: int is safe)
    int aOff[4], bOff[4];
    #pragma unroll
    for (int j = 0; j < 4; ++j) {
        aOff[j] = (rowBase + wn + j * 16 + lrow) * D_DIM;   // B operand (n)
        bOff[j] = (colBase + wm + j * 16 + lrow) * D_DIM;   // A operand (m)
    }

    floatx4 acc[4][4] = {};   // acc[jm][jn]
    #pragma unroll
    for (int ks = 0; ks < 4; ++ks) {
        const int k0 = ks * 32 + lk8;
        short8 afr[4], bfr[4];
        #pragma unroll
        for (int jm = 0; jm < 4; ++jm)
            afr[jm] = *(const short8*)(bbf + (bOff[jm] + k0));
        #pragma unroll
        for (int jn = 0; jn < 4; ++jn)
            bfr[jn] = *(const short8*)(abf + (aOff[jn] + k0));
        #pragma unroll
        for (int jm = 0; jm < 4; ++jm)
            #pragma unroll
            for (int jn = 0; jn < 4; ++jn)
                acc[jm][jn] = __builtin_amdgcn_mfma_f32_16x16x32_bf16(afr[jm], bfr[jn], acc[jm][jn], 0, 0, 0);
    }

    // Preload norms: a2 per jn (scalar per lane), b2 per jm (float4 per lane)
    float an[4];
    floatx4 bq[4];
    #pragma unroll
    for (int jn = 0; jn < 4; ++jn) an[jn] = a2[rowBase + wn + jn * 16 + lrow];
    #pragma unroll
    for (int jm = 0; jm < 4; ++jm) bq[jm] = *(const floatx4*)(b2 + colBase + wm + jm * 16 + mq);

    // Two 64-row chunks: waves with wn==c*64 deposit their finished values,
    // then all 4 waves stream the chunk out with 512B-contiguous segments.
    const int myChunk = wave >> 1;
    #pragma unroll
    for (int c = 0; c < 2; ++c) {
        if (myChunk == c) {
            #pragma unroll
            for (int jn = 0; jn < 4; ++jn) {
                const int nl = jn * 16 + lrow;               // 0..63 within chunk
                #pragma unroll
                for (int jm = 0; jm < 4; ++jm) {
                    floatx4 v;
                    #pragma unroll
                    for (int r = 0; r < 4; ++r) {
                        float d2 = an[jn] + bq[jm][r] - 2.0f * acc[jm][jn][r];
                        d2 = fmaxf(d2, 0.0f);
                        v[r] = -__builtin_amdgcn_sqrtf(d2);
                    }
                    *(floatx4*)(&lt[nl][wm + jm * 16 + mq]) = v;
                }
            }
        }
        __syncthreads();
        const size_t base = (size_t)(rowBase + c * 64) * (size_t)M + (size_t)colBase;
        #pragma unroll
        for (int p = 0; p < 8; ++p) {
            const int row = p * 8 + (tid >> 5);              // 8 rows per pass
            const int col = (tid & 31) * 4;                  // 32 lanes x float4 = 512B/row
            const floatx4 v = *(const floatx4*)(&lt[row][col]);
            __builtin_nontemporal_store(v, (floatx4*)(out + base + (size_t)row * M + col));
        }
        if (c == 0) __syncthreads();   // protect lt before chunk-1 deposits
    }
}

extern "C" void kernel_launch(void* const* d_in, const int* in_sizes, int n_in,
                              void* d_out, int out_size, void* d_ws, size_t ws_size,
                              hipStream_t stream) {
    const float* za = (const float*)d_in[0];
    const float* zb = (const float*)d_in[1];
    const int N = in_sizes[0] / D_DIM;   // 8192
    const int M = in_sizes[1] / D_DIM;   // 8192
    float* out = (float*)d_out;

    // workspace layout: abf [N*128 bf16] | bbf [M*128 bf16] | a2 [N f32] | b2 [M f32]
    char* ws = (char*)d_ws;
    __hip_bfloat16* abf = (__hip_bfloat16*)ws;
    __hip_bfloat16* bbf = (__hip_bfloat16*)(ws + (size_t)N * D_DIM * sizeof(__hip_bfloat16));
    float* a2 = (float*)(ws + (size_t)(N + M) * D_DIM * sizeof(__hip_bfloat16));
    float* b2 = a2 + N;

    prep_kernel<<<(N + M) / 4, 256, 0, stream>>>(za, zb, abf, bbf, a2, b2, N);

    dim3 grid(M / TILE, N / TILE);
    dist_kernel<<<grid, 256, 0, stream>>>(abf, bbf, a2, b2, out, M);
}

// Round 4
// 284.678 us; speedup vs baseline: 1.2292x; 1.1616x over previous
//
#include <hip/hip_runtime.h>
#include <hip/hip_bf16.h>

#define D_DIM 128
#define TILE 128
#define LDS_K (D_DIM + 8)   // bf16 stage rows: +16B pad -> 4-bank row rotation, 2-way (free)
#define LT_K  (D_DIM + 4)   // f32 transpose rows: +4 floats -> 4-bank row rotation

typedef __attribute__((ext_vector_type(8))) short short8;   // 8 bf16 in 4 VGPRs (MFMA A/B frag)
typedef __attribute__((ext_vector_type(4))) float floatx4;  // MFMA C/D frag

// ---------------------------------------------------------------------------
// prep: round fp32 rows to bf16 (stored to ws) and compute row sum-of-squares
// of the ROUNDED values (so d2 = ||a_hat - b_hat||^2 >= 0 exactly).
// ---------------------------------------------------------------------------
__global__ void prep_kernel(const float* __restrict__ za, const float* __restrict__ zb,
                            __hip_bfloat16* __restrict__ abf, __hip_bfloat16* __restrict__ bbf,
                            float* __restrict__ a2, float* __restrict__ b2, int N) {
    int r = blockIdx.x * 4 + (threadIdx.x >> 6);
    int lane = threadIdx.x & 63;
    const float* src; __hip_bfloat16* dst; float* nrm; int row;
    if (r < N) { src = za; dst = abf; nrm = a2; row = r; }
    else       { src = zb; dst = bbf; nrm = b2; row = r - N; }
    const float2 v = ((const float2*)(src + (size_t)row * D_DIM))[lane];
    __hip_bfloat16 h0 = __float2bfloat16(v.x);
    __hip_bfloat16 h1 = __float2bfloat16(v.y);
    float f0 = __bfloat162float(h0), f1 = __bfloat162float(h1);
    float ss = f0 * f0 + f1 * f1;
    ushort2 st;
    st.x = *(const unsigned short*)&h0;
    st.y = *(const unsigned short*)&h1;
    ((ushort2*)(dst + (size_t)row * D_DIM))[lane] = st;
    #pragma unroll
    for (int off = 32; off; off >>= 1) ss += __shfl_down(ss, off, 64);
    if (lane == 0) nrm[row] = ss;
}

// ---------------------------------------------------------------------------
// dist v4: R0's proven LDS-staged input path (fastest measured config at
// equal machine speed) + LDS-TRANSPOSE EPILOGUE with REGULAR stores.
// R3's regression is attributed to nontemporal stores (vmcnt(0) drain at the
// barrier waits for HBM-latency acks) and/or direct-from-L2 frag loads (4x
// VMEM segment traffic); both reverted here.
//
// Epilogue: the As/Bs staging LDS (69.6KB) is dead after the MFMA loop --
// reuse it as a 128 x (128+4) f32 buffer. Deposit -sqrt(max(a2+b2-2ab,0))
// with b128 writes (operand-swapped MFMA makes each lane's 4 acc regs 4
// consecutive m), then all 256 threads stream rows out: each store inst
// covers 2 rows x 512B contiguous (vs 16 rows x 64B for direct frag stores).
//
// Verified gfx950 layouts (learn_hip m89/m91), operand-swapped:
//   acc = mfma(frag from Bs (m rows), frag from As (n rows))
//   acc[jm][jn][r] <-> m_local = wm + jm*16 + (lane>>4)*4 + r
//                      n_local = wn + jn*16 + (lane&15)
// ---------------------------------------------------------------------------
__global__ __launch_bounds__(256, 2)
void dist_kernel(const __hip_bfloat16* __restrict__ abf, const __hip_bfloat16* __restrict__ bbf,
                 const float* __restrict__ a2, const float* __restrict__ b2,
                 float* __restrict__ out, int M) {
    __shared__ __align__(16) char smem[2 * TILE * LDS_K * sizeof(__hip_bfloat16)]; // 69632 B
    typedef __hip_bfloat16 bfrow_t[LDS_K];
    typedef float frow_t[LT_K];
    bfrow_t* As = reinterpret_cast<bfrow_t*>(smem);
    bfrow_t* Bs = reinterpret_cast<bfrow_t*>(smem + TILE * LDS_K * sizeof(__hip_bfloat16));
    frow_t*  lt = reinterpret_cast<frow_t*>(smem);   // 128*132*4 = 67584 B, fits

    const int rowBase = blockIdx.y * TILE;   // n: into z_anc
    const int colBase = blockIdx.x * TILE;   // m: into z_pos_neg
    const int tid = threadIdx.x;

    // Stage both 128x128 bf16 tiles: 16 chunks of 8 bf16 per row, coalesced.
    #pragma unroll
    for (int pass = 0; pass < 8; ++pass) {
        int idx = pass * 256 + tid;          // 0..2047
        int row = idx >> 4;
        int kc  = (idx & 15) * 8;
        uint4 va = *(const uint4*)(abf + ((size_t)(rowBase + row) * D_DIM + kc));
        *(uint4*)(&As[row][kc]) = va;
        uint4 vb = *(const uint4*)(bbf + ((size_t)(colBase + row) * D_DIM + kc));
        *(uint4*)(&Bs[row][kc]) = vb;
    }
    __syncthreads();

    const int wave = tid >> 6;
    const int lane = tid & 63;
    const int wn = (wave >> 1) * 64;         // wave n-offset in tile
    const int wm = (wave & 1) * 64;          // wave m-offset in tile
    const int lrow = lane & 15;
    const int lk8  = (lane >> 4) * 8;
    const int mq   = (lane >> 4) * 4;

    floatx4 acc[4][4] = {};   // acc[jm][jn]
    #pragma unroll
    for (int ks = 0; ks < 4; ++ks) {
        const int k0 = ks * 32 + lk8;
        short8 afr[4], bfr[4];
        #pragma unroll
        for (int jm = 0; jm < 4; ++jm)
            afr[jm] = *(const short8*)(&Bs[wm + jm * 16 + lrow][k0]);   // A-op: m rows
        #pragma unroll
        for (int jn = 0; jn < 4; ++jn)
            bfr[jn] = *(const short8*)(&As[wn + jn * 16 + lrow][k0]);   // B-op: n rows
        #pragma unroll
        for (int jm = 0; jm < 4; ++jm)
            #pragma unroll
            for (int jn = 0; jn < 4; ++jn)
                acc[jm][jn] = __builtin_amdgcn_mfma_f32_16x16x32_bf16(afr[jm], bfr[jn], acc[jm][jn], 0, 0, 0);
    }

    // Norms: a2 scalar per jn-row, b2 float4 per jm-quad.
    float an[4];
    floatx4 bq[4];
    #pragma unroll
    for (int jn = 0; jn < 4; ++jn) an[jn] = a2[rowBase + wn + jn * 16 + lrow];
    #pragma unroll
    for (int jm = 0; jm < 4; ++jm) bq[jm] = *(const floatx4*)(b2 + colBase + wm + jm * 16 + mq);

    __syncthreads();   // all waves done reading As/Bs before aliasing as lt

    // Deposit finished values: 16 x ds_write_b128 per thread.
    #pragma unroll
    for (int jn = 0; jn < 4; ++jn) {
        const int nl = wn + jn * 16 + lrow;              // 0..127
        #pragma unroll
        for (int jm = 0; jm < 4; ++jm) {
            floatx4 v;
            #pragma unroll
            for (int r = 0; r < 4; ++r) {
                float d2 = an[jn] + bq[jm][r] - 2.0f * acc[jm][jn][r];
                d2 = fmaxf(d2, 0.0f);
                v[r] = -__builtin_amdgcn_sqrtf(d2);
            }
            *(floatx4*)(&lt[nl][wm + jm * 16 + mq]) = v;
        }
    }
    __syncthreads();

    // Cooperative store: each pass, a wave covers 2 rows x 512B contiguous.
    const size_t base = (size_t)rowBase * (size_t)M + (size_t)colBase;
    #pragma unroll
    for (int p = 0; p < 16; ++p) {
        const int row = p * 8 + (tid >> 5);              // 0..127
        const int col = (tid & 31) * 4;                  // 32 lanes x float4 = 512B
        const floatx4 v = *(const floatx4*)(&lt[row][col]);
        *(floatx4*)(out + base + (size_t)row * M + col) = v;
    }
}

extern "C" void kernel_launch(void* const* d_in, const int* in_sizes, int n_in,
                              void* d_out, int out_size, void* d_ws, size_t ws_size,
                              hipStream_t stream) {
    const float* za = (const float*)d_in[0];
    const float* zb = (const float*)d_in[1];
    const int N = in_sizes[0] / D_DIM;   // 8192
    const int M = in_sizes[1] / D_DIM;   // 8192
    float* out = (float*)d_out;

    // workspace layout: abf [N*128 bf16] | bbf [M*128 bf16] | a2 [N f32] | b2 [M f32]
    char* ws = (char*)d_ws;
    __hip_bfloat16* abf = (__hip_bfloat16*)ws;
    __hip_bfloat16* bbf = (__hip_bfloat16*)(ws + (size_t)N * D_DIM * sizeof(__hip_bfloat16));
    float* a2 = (float*)(ws + (size_t)(N + M) * D_DIM * sizeof(__hip_bfloat16));
    float* b2 = a2 + N;

    prep_kernel<<<(N + M) / 4, 256, 0, stream>>>(za, zb, abf, bbf, a2, b2, N);

    dim3 grid(M / TILE, N / TILE);
    dist_kernel<<<grid, 256, 0, stream>>>(abf, bbf, a2, b2, out, M);
}